// Round 9
// baseline (335.382 us; speedup 1.0000x reference)
//
#include <hip/hip_runtime.h>

typedef __bf16 bf16_t;
typedef __bf16 bf16x8 __attribute__((ext_vector_type(8)));
typedef __bf16 bf16x4 __attribute__((ext_vector_type(4)));
typedef float  f32x4  __attribute__((ext_vector_type(4)));

// ---------------------------------------------------------------------------
// Workspace layout (floats unless noted):
//   A   : [4096][256] f32   (xf @ W1[0:26])                          4 MB
//   C   : [4096][256] f32   (xf @ W1[26:52] + qst @ W1[52:180] + b1) 4 MB
//   Wt  : 3 x [256][256] bf16, g2/g3/g4 weights transposed [out][in] 384 KB
//   xg  : [64][256] f32     (pair-summed g output)                   64 KB
//   cnt : [64] int          (per-batch completion counters)          256 B
// ---------------------------------------------------------------------------

// swizzled LDS column index: 16B-block XOR on row low bits.
__device__ __forceinline__ int swz(int row, int col) {
  return (((col >> 3) ^ (row & 7)) << 3) | (col & 7);
}

// ---------------- prep: A, C, weight transpose+cast, zero xg/cnt -----------
__global__ __launch_bounds__(256) void rn_prep_kernel(
    const float* __restrict__ x, const float* __restrict__ qst,
    const float* __restrict__ g1w, const float* __restrict__ g1b,
    const float* __restrict__ g2w, const float* __restrict__ g3w,
    const float* __restrict__ g4w,
    float* __restrict__ A, float* __restrict__ C,
    bf16_t* __restrict__ Wt, float* __restrict__ xg, int* __restrict__ cnt)
{
  __shared__ float T[64][65];   // transpose tile (only used by that branch)
  int blk = blockIdx.x;
  int n   = threadIdx.x;  // 0..255
  if (blk < 256) {
    // block = (b, jg): rows jg*16 .. jg*16+15 of batch b; thread = output col n
    int b  = blk >> 2;
    int jg = (blk & 3) * 16;
    float accQ = g1b[n];
    const float* qb = qst + b * 128;
    #pragma unroll 8
    for (int qi = 0; qi < 128; ++qi)
      accQ += qb[qi] * g1w[(52 + qi) * 256 + n];

    float w24 = g1w[24 * 256 + n], w25 = g1w[25 * 256 + n];
    float w50 = g1w[50 * 256 + n], w51 = g1w[51 * 256 + n];
    float accA[16], accC[16];
    #pragma unroll
    for (int t = 0; t < 16; ++t) {
      int j = jg + t;
      // faithful to (a/d - d/2)/(d/2.0) float arithmetic, d=8 (exact pow2 ops)
      float cx = ((float)j * 0.125f - 4.0f) * 0.25f;
      float cy = ((float)(j & 7) - 4.0f) * 0.25f;
      accA[t] = cx * w24 + cy * w25;
      accC[t] = accQ + cx * w50 + cy * w51;
    }
    for (int c = 0; c < 24; ++c) {
      float wa = g1w[c * 256 + n];
      float wc = g1w[(26 + c) * 256 + n];
      const float* xc = x + (b * 24 + c) * 64 + jg;
      #pragma unroll
      for (int t = 0; t < 16; ++t) {
        float xv = xc[t];   // uniform per thread -> scalar load
        accA[t] += xv * wa;
        accC[t] += xv * wc;
      }
    }
    #pragma unroll
    for (int t = 0; t < 16; ++t) {
      A[(b * 64 + jg + t) * 256 + n] = accA[t];
      C[(b * 64 + jg + t) * 256 + n] = accC[t];
    }
  } else if (blk < 256 + 48) {
    // LDS-tiled transpose: g2/g3/g4 [in(k)][out(no)] f32 -> bf16 [no][k]
    int t   = blk - 256;
    int mat = t >> 4;                 // 0..2
    int tl  = t & 15;                 // 4x4 tiles of 64x64
    int kt  = (tl & 3) * 64;
    int nt_ = (tl >> 2) * 64;
    const float* W = (mat == 0) ? g2w : (mat == 1 ? g3w : g4w);
    int lane = n & 63, w = n >> 6;
    #pragma unroll
    for (int it = 0; it < 16; ++it) {
      int kl = w * 16 + it;
      T[kl][lane] = W[(kt + kl) * 256 + nt_ + lane];   // coalesced 256B/wave
    }
    __syncthreads();
    #pragma unroll
    for (int it = 0; it < 16; ++it) {
      int nl = w * 16 + it;
      Wt[mat * 65536 + (nt_ + nl) * 256 + kt + lane] = (bf16_t)T[lane][nl];
    }
  } else {
    int idx = (blk - (256 + 48)) * 256 + n;  // 65 blocks cover 16384 + 64
    if (idx < 16384) xg[idx] = 0.f;
    else if (idx < 16384 + 64) cnt[idx - 16384] = 0;
  }
}

// ---------------- main fused g-MLP (layers 2..4) + pair sum + f ------------
// R5's main kernel VERBATIM (the 153us local optimum: one block per
// (b, i-pair), M=128, 4 waves each owning n slice [wave*64,+64) x all 128 m,
// acc = 4x8 f32x4 = 128 AGPRs, operand-swapped MFMA, K-loop = 12 loads then
// 32 independent MFMAs). R6/R7/R8 proved every restructure of this loop
// (occupancy forcing, ping-pong pipelining, unroll-disable) regresses.
// Only additions vs R5: bias via uniform ternary (no scratch pointer array)
// and the R7 f-MLP tail (proven to save ~33us of launch/kernel overhead),
// with the completion flag overlaid in hbuf so LDS stays exactly 64 KB.
__global__ __launch_bounds__(256, 2) void rn_main_kernel(
    const float* __restrict__ A, const float* __restrict__ C,
    const bf16_t* __restrict__ Wt,
    const float* __restrict__ g2b, const float* __restrict__ g3b,
    const float* __restrict__ g4b,
    float* __restrict__ xg, int* __restrict__ cnt,
    const float* __restrict__ f1w, const float* __restrict__ f1b,
    const float* __restrict__ f2w, const float* __restrict__ f2b,
    const float* __restrict__ f3w, const float* __restrict__ f3b,
    float* __restrict__ out)
{
  __shared__ bf16_t hbuf[128][256];   // exactly 64 KB, XOR-swizzled cols
  int* s_flag = (int*)&hbuf[127][252]; // overlay: written only after L-loop

  int tid  = threadIdx.x;
  int bx   = blockIdx.x;
  int b    = bx >> 5;          // batch
  int ip   = bx & 31;          // i-pair: i = 2*ip, 2*ip+1
  int lane = tid & 63;
  int wave = tid >> 6;
  int n0   = wave * 64;

  // ---- build h1 rows: row = ii*64 + j = relu(A[b,j,:] + C[b,2ip+ii,:]) ----
  {
    const float* Ab = A + (size_t)b * 64 * 256;
    const float* Cr = C + ((size_t)b * 64 + ip * 2) * 256;
    #pragma unroll
    for (int it = 0; it < 16; ++it) {
      int g = it * 256 + tid;
      int j = g >> 6;
      int n = (g & 63) * 4;
      const float4 a4 = *(const float4*)(Ab + j * 256 + n);
      const float4 c0 = *(const float4*)(Cr + n);
      const float4 c1 = *(const float4*)(Cr + 256 + n);
      bf16x4 v0, v1;
      v0[0] = (bf16_t)fmaxf(a4.x + c0.x, 0.f);
      v0[1] = (bf16_t)fmaxf(a4.y + c0.y, 0.f);
      v0[2] = (bf16_t)fmaxf(a4.z + c0.z, 0.f);
      v0[3] = (bf16_t)fmaxf(a4.w + c0.w, 0.f);
      v1[0] = (bf16_t)fmaxf(a4.x + c1.x, 0.f);
      v1[1] = (bf16_t)fmaxf(a4.y + c1.y, 0.f);
      v1[2] = (bf16_t)fmaxf(a4.z + c1.z, 0.f);
      v1[3] = (bf16_t)fmaxf(a4.w + c1.w, 0.f);
      *(bf16x4*)&hbuf[j][swz(j, n)] = v0;
      *(bf16x4*)&hbuf[64 + j][swz(64 + j, n)] = v1;
    }
  }

  int r = lane & 15;     // 16-dim index within MFMA tile
  int q = lane >> 4;     // quad: k-chunk selector / D-row group

  for (int L = 0; L < 3; ++L) {
    __syncthreads();     // h ready for reads
    const bf16_t* W = Wt + L * 65536;
    const float* bias = (L == 0) ? g2b : (L == 1 ? g3b : g4b);

    f32x4 acc[4][8];     // [nt][mt]
    #pragma unroll
    for (int nt = 0; nt < 4; ++nt)
      #pragma unroll
      for (int mt = 0; mt < 8; ++mt)
        #pragma unroll
        for (int e = 0; e < 4; ++e) acc[nt][mt][e] = 0.f;

    #pragma unroll
    for (int ks = 0; ks < 8; ++ks) {
      int k0 = ks * 32 + q * 8;    // this lane's 8-element k-run
      bf16x8 wf[4], hf[8];
      #pragma unroll
      for (int nt = 0; nt < 4; ++nt)
        wf[nt] = *(const bf16x8*)&W[(n0 + nt * 16 + r) * 256 + k0];
      #pragma unroll
      for (int mt = 0; mt < 8; ++mt) {
        int row = mt * 16 + r;
        hf[mt] = *(const bf16x8*)&hbuf[row][swz(row, k0)];
      }
      #pragma unroll
      for (int nt = 0; nt < 4; ++nt)
        #pragma unroll
        for (int mt = 0; mt < 8; ++mt)
          acc[nt][mt] = __builtin_amdgcn_mfma_f32_16x16x32_bf16(
              wf[nt], hf[mt], acc[nt][mt], 0, 0, 0);
    }

    float4 bv[4];        // biases for n = n0 + nt*16 + q*4 + rg
    #pragma unroll
    for (int nt = 0; nt < 4; ++nt)
      bv[nt] = *(const float4*)&bias[n0 + nt * 16 + q * 4];

    if (L < 2) {
      __syncthreads();   // all reads of hbuf done -> safe to overwrite
      #pragma unroll
      for (int nt = 0; nt < 4; ++nt) {
        int col = n0 + nt * 16 + q * 4;
        #pragma unroll
        for (int mt = 0; mt < 8; ++mt) {
          int row = mt * 16 + r;
          f32x4 a = acc[nt][mt];
          bf16x4 v;
          v[0] = (bf16_t)fmaxf(a[0] + bv[nt].x, 0.f);
          v[1] = (bf16_t)fmaxf(a[1] + bv[nt].y, 0.f);
          v[2] = (bf16_t)fmaxf(a[2] + bv[nt].z, 0.f);
          v[3] = (bf16_t)fmaxf(a[3] + bv[nt].w, 0.f);
          *(bf16x4*)&hbuf[row][swz(row, col)] = v;
        }
      }
    } else {
      // last layer: bias+relu fp32, sum over all 128 m-rows, atomic to xg.
      #pragma unroll
      for (int nt = 0; nt < 4; ++nt) {
        float p0 = 0.f, p1 = 0.f, p2 = 0.f, p3 = 0.f;
        #pragma unroll
        for (int mt = 0; mt < 8; ++mt) {
          p0 += fmaxf(acc[nt][mt][0] + bv[nt].x, 0.f);
          p1 += fmaxf(acc[nt][mt][1] + bv[nt].y, 0.f);
          p2 += fmaxf(acc[nt][mt][2] + bv[nt].z, 0.f);
          p3 += fmaxf(acc[nt][mt][3] + bv[nt].w, 0.f);
        }
        #pragma unroll
        for (int d = 1; d < 16; d <<= 1) {
          p0 += __shfl_xor(p0, d, 64);
          p1 += __shfl_xor(p1, d, 64);
          p2 += __shfl_xor(p2, d, 64);
          p3 += __shfl_xor(p3, d, 64);
        }
        if (r == 0) {
          int n = b * 256 + n0 + nt * 16 + q * 4;
          atomicAdd(&xg[n + 0], p0);
          atomicAdd(&xg[n + 1], p1);
          atomicAdd(&xg[n + 2], p2);
          atomicAdd(&xg[n + 3], p3);
        }
      }
    }
  }

  // ---- last block for this batch runs the f-MLP + log_softmax inline ----
  __syncthreads();   // drains vmcnt before barrier -> our atomics are done
  if (tid == 0) {
    __threadfence();
    int old = __hip_atomic_fetch_add(&cnt[b], 1, __ATOMIC_ACQ_REL,
                                     __HIP_MEMORY_SCOPE_AGENT);
    *s_flag = (old == 31);
  }
  __syncthreads();
  if (*s_flag) {
    float* xs = (float*)&hbuf[0][0];       // reuse LDS as fp32 scratch
    float* t1 = xs + 256;
    float* t2 = t1 + 256;
    float* lg = t2 + 256;
    float* ls = lg + 28;
    xs[tid] = __hip_atomic_load(&xg[b * 256 + tid], __ATOMIC_RELAXED,
                                __HIP_MEMORY_SCOPE_AGENT);
    __syncthreads();
    float acc1 = f1b[tid];
    for (int k = 0; k < 256; ++k) acc1 += xs[k] * f1w[k * 256 + tid];
    t1[tid] = fmaxf(acc1, 0.f);
    __syncthreads();
    float acc2 = f2b[tid];
    for (int k = 0; k < 256; ++k) acc2 += t1[k] * f2w[k * 256 + tid];
    t2[tid] = fmaxf(acc2, 0.f);
    __syncthreads();
    if (tid < 28) {
      float a2 = f3b[tid];
      for (int k = 0; k < 256; ++k) a2 += t2[k] * f3w[k * 28 + tid];
      lg[tid] = a2;
    }
    __syncthreads();
    if (tid == 0) {
      float m = lg[0];
      for (int j = 1; j < 28; ++j) m = fmaxf(m, lg[j]);
      float se = 0.f;
      for (int j = 0; j < 28; ++j) se += expf(lg[j] - m);
      ls[0] = m + logf(se);
    }
    __syncthreads();
    if (tid < 28) out[b * 28 + tid] = lg[tid] - ls[0];
  }
}

// ---------------------------------------------------------------------------
extern "C" void kernel_launch(void* const* d_in, const int* in_sizes, int n_in,
                              void* d_out, int out_size, void* d_ws, size_t ws_size,
                              hipStream_t stream) {
  (void)in_sizes; (void)n_in; (void)out_size; (void)ws_size;
  const float* x   = (const float*)d_in[0];
  const float* qst = (const float*)d_in[1];
  const float* g1w = (const float*)d_in[2];
  const float* g1b = (const float*)d_in[3];
  const float* g2w = (const float*)d_in[4];
  const float* g2b = (const float*)d_in[5];
  const float* g3w = (const float*)d_in[6];
  const float* g3b = (const float*)d_in[7];
  const float* g4w = (const float*)d_in[8];
  const float* g4b = (const float*)d_in[9];
  const float* f1w = (const float*)d_in[10];
  const float* f1b = (const float*)d_in[11];
  const float* f2w = (const float*)d_in[12];
  const float* f2b = (const float*)d_in[13];
  const float* f3w = (const float*)d_in[14];
  const float* f3b = (const float*)d_in[15];
  float* out = (float*)d_out;

  float*  A  = (float*)d_ws;
  float*  C  = A + 4096 * 256;
  bf16_t* Wt = (bf16_t*)(C + 4096 * 256);
  float*  xg = (float*)((char*)Wt + 3 * 65536 * sizeof(bf16_t));
  int*    cnt = (int*)(xg + 64 * 256);

  rn_prep_kernel<<<256 + 48 + 65, 256, 0, stream>>>(
      x, qst, g1w, g1b, g2w, g3w, g4w, A, C, Wt, xg, cnt);
  rn_main_kernel<<<2048, 256, 0, stream>>>(
      A, C, Wt, g2b, g3b, g4b, xg, cnt,
      f1w, f1b, f2w, f2b, f3w, f3b, out);
}

// Round 10
// 302.377 us; speedup vs baseline: 1.1092x; 1.1092x over previous
//
#include <hip/hip_runtime.h>

typedef __bf16 bf16_t;
typedef __bf16 bf16x8 __attribute__((ext_vector_type(8)));
typedef __bf16 bf16x4 __attribute__((ext_vector_type(4)));
typedef float  f32x4  __attribute__((ext_vector_type(4)));

// ---------------------------------------------------------------------------
// Workspace layout (floats unless noted):
//   A   : [4096][256] f32   (xf @ W1[0:26])                          4 MB
//   C   : [4096][256] f32   (xf @ W1[26:52] + qst @ W1[52:180] + b1) 4 MB
//   Wt  : 3 x [256][256] bf16, g2/g3/g4 weights transposed [out][in] 384 KB
//   xg  : [64][256] f32     (pair-summed g output)                   64 KB
//   cnt : [64] int          (per-batch completion counters)          256 B
// ---------------------------------------------------------------------------

// swizzled LDS column index: 16B-block XOR on row low bits.
__device__ __forceinline__ int swz(int row, int col) {
  return (((col >> 3) ^ (row & 7)) << 3) | (col & 7);
}

// ---------------- prep: A, C, weight transpose+cast, zero xg/cnt -----------
__global__ __launch_bounds__(256) void rn_prep_kernel(
    const float* __restrict__ x, const float* __restrict__ qst,
    const float* __restrict__ g1w, const float* __restrict__ g1b,
    const float* __restrict__ g2w, const float* __restrict__ g3w,
    const float* __restrict__ g4w,
    float* __restrict__ A, float* __restrict__ C,
    bf16_t* __restrict__ Wt, float* __restrict__ xg, int* __restrict__ cnt)
{
  __shared__ float T[64][65];   // transpose tile (only used by that branch)
  int blk = blockIdx.x;
  int n   = threadIdx.x;  // 0..255
  if (blk < 256) {
    // block = (b, jg): rows jg*16 .. jg*16+15 of batch b; thread = output col n
    int b  = blk >> 2;
    int jg = (blk & 3) * 16;
    float accQ = g1b[n];
    const float* qb = qst + b * 128;
    #pragma unroll 8
    for (int qi = 0; qi < 128; ++qi)
      accQ += qb[qi] * g1w[(52 + qi) * 256 + n];

    float w24 = g1w[24 * 256 + n], w25 = g1w[25 * 256 + n];
    float w50 = g1w[50 * 256 + n], w51 = g1w[51 * 256 + n];
    float accA[16], accC[16];
    #pragma unroll
    for (int t = 0; t < 16; ++t) {
      int j = jg + t;
      // faithful to (a/d - d/2)/(d/2.0) float arithmetic, d=8 (exact pow2 ops)
      float cx = ((float)j * 0.125f - 4.0f) * 0.25f;
      float cy = ((float)(j & 7) - 4.0f) * 0.25f;
      accA[t] = cx * w24 + cy * w25;
      accC[t] = accQ + cx * w50 + cy * w51;
    }
    for (int c = 0; c < 24; ++c) {
      float wa = g1w[c * 256 + n];
      float wc = g1w[(26 + c) * 256 + n];
      const float* xc = x + (b * 24 + c) * 64 + jg;
      #pragma unroll
      for (int t = 0; t < 16; ++t) {
        float xv = xc[t];   // uniform per thread -> scalar load
        accA[t] += xv * wa;
        accC[t] += xv * wc;
      }
    }
    #pragma unroll
    for (int t = 0; t < 16; ++t) {
      A[(b * 64 + jg + t) * 256 + n] = accA[t];
      C[(b * 64 + jg + t) * 256 + n] = accC[t];
    }
  } else if (blk < 256 + 48) {
    // LDS-tiled transpose: g2/g3/g4 [in(k)][out(no)] f32 -> bf16 [no][k]
    int t   = blk - 256;
    int mat = t >> 4;                 // 0..2
    int tl  = t & 15;                 // 4x4 tiles of 64x64
    int kt  = (tl & 3) * 64;
    int nt_ = (tl >> 2) * 64;
    const float* W = (mat == 0) ? g2w : (mat == 1 ? g3w : g4w);
    int lane = n & 63, w = n >> 6;
    #pragma unroll
    for (int it = 0; it < 16; ++it) {
      int kl = w * 16 + it;
      T[kl][lane] = W[(kt + kl) * 256 + nt_ + lane];   // coalesced 256B/wave
    }
    __syncthreads();
    #pragma unroll
    for (int it = 0; it < 16; ++it) {
      int nl = w * 16 + it;
      Wt[mat * 65536 + (nt_ + nl) * 256 + kt + lane] = (bf16_t)T[lane][nl];
    }
  } else {
    int idx = (blk - (256 + 48)) * 256 + n;  // 65 blocks cover 16384 + 64
    if (idx < 16384) xg[idx] = 0.f;
    else if (idx < 16384 + 64) cnt[idx - 16384] = 0;
  }
}

// ---------------- main fused g-MLP (layers 2..4) + pair sum + f ------------
// R5's main kernel (the 153us local optimum: one block per (b, i-pair),
// M=128, 4 waves each owning n slice [wave*64,+64) x all 128 m, acc = 4x8
// f32x4 = 128 AGPRs, operand-swapped MFMA, K-loop = 12 loads then 32
// independent MFMAs) + the R7 f-MLP tail.
// CRITICAL (R8/R9 lesson): with the fused tail the function body exceeds the
// compiler's unroll-size heuristic and the L-loop silently stops being fully
// unrolled -> 153us becomes 263us (R9 measured; R8's explicit
// unroll(disable) measured identically). #pragma unroll forces the R5
// codegen back. Do NOT remove it.
__global__ __launch_bounds__(256, 2) void rn_main_kernel(
    const float* __restrict__ A, const float* __restrict__ C,
    const bf16_t* __restrict__ Wt,
    const float* __restrict__ g2b, const float* __restrict__ g3b,
    const float* __restrict__ g4b,
    float* __restrict__ xg, int* __restrict__ cnt,
    const float* __restrict__ f1w, const float* __restrict__ f1b,
    const float* __restrict__ f2w, const float* __restrict__ f2b,
    const float* __restrict__ f3w, const float* __restrict__ f3b,
    float* __restrict__ out)
{
  __shared__ bf16_t hbuf[128][256];   // exactly 64 KB, XOR-swizzled cols
  int* s_flag = (int*)&hbuf[127][252]; // overlay: written only after L-loop

  int tid  = threadIdx.x;
  int bx   = blockIdx.x;
  int b    = bx >> 5;          // batch
  int ip   = bx & 31;          // i-pair: i = 2*ip, 2*ip+1
  int lane = tid & 63;
  int wave = tid >> 6;
  int n0   = wave * 64;

  // ---- build h1 rows: row = ii*64 + j = relu(A[b,j,:] + C[b,2ip+ii,:]) ----
  {
    const float* Ab = A + (size_t)b * 64 * 256;
    const float* Cr = C + ((size_t)b * 64 + ip * 2) * 256;
    #pragma unroll
    for (int it = 0; it < 16; ++it) {
      int g = it * 256 + tid;
      int j = g >> 6;
      int n = (g & 63) * 4;
      const float4 a4 = *(const float4*)(Ab + j * 256 + n);
      const float4 c0 = *(const float4*)(Cr + n);
      const float4 c1 = *(const float4*)(Cr + 256 + n);
      bf16x4 v0, v1;
      v0[0] = (bf16_t)fmaxf(a4.x + c0.x, 0.f);
      v0[1] = (bf16_t)fmaxf(a4.y + c0.y, 0.f);
      v0[2] = (bf16_t)fmaxf(a4.z + c0.z, 0.f);
      v0[3] = (bf16_t)fmaxf(a4.w + c0.w, 0.f);
      v1[0] = (bf16_t)fmaxf(a4.x + c1.x, 0.f);
      v1[1] = (bf16_t)fmaxf(a4.y + c1.y, 0.f);
      v1[2] = (bf16_t)fmaxf(a4.z + c1.z, 0.f);
      v1[3] = (bf16_t)fmaxf(a4.w + c1.w, 0.f);
      *(bf16x4*)&hbuf[j][swz(j, n)] = v0;
      *(bf16x4*)&hbuf[64 + j][swz(64 + j, n)] = v1;
    }
  }

  int r = lane & 15;     // 16-dim index within MFMA tile
  int q = lane >> 4;     // quad: k-chunk selector / D-row group

  #pragma unroll
  for (int L = 0; L < 3; ++L) {
    __syncthreads();     // h ready for reads
    const bf16_t* W = Wt + L * 65536;
    const float* bias = (L == 0) ? g2b : (L == 1 ? g3b : g4b);

    f32x4 acc[4][8];     // [nt][mt]
    #pragma unroll
    for (int nt = 0; nt < 4; ++nt)
      #pragma unroll
      for (int mt = 0; mt < 8; ++mt)
        #pragma unroll
        for (int e = 0; e < 4; ++e) acc[nt][mt][e] = 0.f;

    #pragma unroll
    for (int ks = 0; ks < 8; ++ks) {
      int k0 = ks * 32 + q * 8;    // this lane's 8-element k-run
      bf16x8 wf[4], hf[8];
      #pragma unroll
      for (int nt = 0; nt < 4; ++nt)
        wf[nt] = *(const bf16x8*)&W[(n0 + nt * 16 + r) * 256 + k0];
      #pragma unroll
      for (int mt = 0; mt < 8; ++mt) {
        int row = mt * 16 + r;
        hf[mt] = *(const bf16x8*)&hbuf[row][swz(row, k0)];
      }
      #pragma unroll
      for (int nt = 0; nt < 4; ++nt)
        #pragma unroll
        for (int mt = 0; mt < 8; ++mt)
          acc[nt][mt] = __builtin_amdgcn_mfma_f32_16x16x32_bf16(
              wf[nt], hf[mt], acc[nt][mt], 0, 0, 0);
    }

    float4 bv[4];        // biases for n = n0 + nt*16 + q*4 + rg
    #pragma unroll
    for (int nt = 0; nt < 4; ++nt)
      bv[nt] = *(const float4*)&bias[n0 + nt * 16 + q * 4];

    if (L < 2) {
      __syncthreads();   // all reads of hbuf done -> safe to overwrite
      #pragma unroll
      for (int nt = 0; nt < 4; ++nt) {
        int col = n0 + nt * 16 + q * 4;
        #pragma unroll
        for (int mt = 0; mt < 8; ++mt) {
          int row = mt * 16 + r;
          f32x4 a = acc[nt][mt];
          bf16x4 v;
          v[0] = (bf16_t)fmaxf(a[0] + bv[nt].x, 0.f);
          v[1] = (bf16_t)fmaxf(a[1] + bv[nt].y, 0.f);
          v[2] = (bf16_t)fmaxf(a[2] + bv[nt].z, 0.f);
          v[3] = (bf16_t)fmaxf(a[3] + bv[nt].w, 0.f);
          *(bf16x4*)&hbuf[row][swz(row, col)] = v;
        }
      }
    } else {
      // last layer: bias+relu fp32, sum over all 128 m-rows, atomic to xg.
      #pragma unroll
      for (int nt = 0; nt < 4; ++nt) {
        float p0 = 0.f, p1 = 0.f, p2 = 0.f, p3 = 0.f;
        #pragma unroll
        for (int mt = 0; mt < 8; ++mt) {
          p0 += fmaxf(acc[nt][mt][0] + bv[nt].x, 0.f);
          p1 += fmaxf(acc[nt][mt][1] + bv[nt].y, 0.f);
          p2 += fmaxf(acc[nt][mt][2] + bv[nt].z, 0.f);
          p3 += fmaxf(acc[nt][mt][3] + bv[nt].w, 0.f);
        }
        #pragma unroll
        for (int d = 1; d < 16; d <<= 1) {
          p0 += __shfl_xor(p0, d, 64);
          p1 += __shfl_xor(p1, d, 64);
          p2 += __shfl_xor(p2, d, 64);
          p3 += __shfl_xor(p3, d, 64);
        }
        if (r == 0) {
          int n = b * 256 + n0 + nt * 16 + q * 4;
          atomicAdd(&xg[n + 0], p0);
          atomicAdd(&xg[n + 1], p1);
          atomicAdd(&xg[n + 2], p2);
          atomicAdd(&xg[n + 3], p3);
        }
      }
    }
  }

  // ---- last block for this batch runs the f-MLP + log_softmax inline ----
  __syncthreads();   // drains vmcnt before barrier -> our atomics are done
  if (tid == 0) {
    __threadfence();
    int old = __hip_atomic_fetch_add(&cnt[b], 1, __ATOMIC_ACQ_REL,
                                     __HIP_MEMORY_SCOPE_AGENT);
    *s_flag = (old == 31);
  }
  __syncthreads();
  if (*s_flag) {
    float* xs = (float*)&hbuf[0][0];       // reuse LDS as fp32 scratch
    float* t1 = xs + 256;
    float* t2 = t1 + 256;
    float* lg = t2 + 256;
    float* ls = lg + 28;
    xs[tid] = __hip_atomic_load(&xg[b * 256 + tid], __ATOMIC_RELAXED,
                                __HIP_MEMORY_SCOPE_AGENT);
    __syncthreads();
    float acc1 = f1b[tid];
    for (int k = 0; k < 256; ++k) acc1 += xs[k] * f1w[k * 256 + tid];
    t1[tid] = fmaxf(acc1, 0.f);
    __syncthreads();
    float acc2 = f2b[tid];
    for (int k = 0; k < 256; ++k) acc2 += t1[k] * f2w[k * 256 + tid];
    t2[tid] = fmaxf(acc2, 0.f);
    __syncthreads();
    if (tid < 28) {
      float a2 = f3b[tid];
      for (int k = 0; k < 256; ++k) a2 += t2[k] * f3w[k * 28 + tid];
      lg[tid] = a2;
    }
    __syncthreads();
    if (tid == 0) {
      float m = lg[0];
      for (int j = 1; j < 28; ++j) m = fmaxf(m, lg[j]);
      float se = 0.f;
      for (int j = 0; j < 28; ++j) se += expf(lg[j] - m);
      ls[0] = m + logf(se);
    }
    __syncthreads();
    if (tid < 28) out[b * 28 + tid] = lg[tid] - ls[0];
  }
}

// ---------------------------------------------------------------------------
extern "C" void kernel_launch(void* const* d_in, const int* in_sizes, int n_in,
                              void* d_out, int out_size, void* d_ws, size_t ws_size,
                              hipStream_t stream) {
  (void)in_sizes; (void)n_in; (void)out_size; (void)ws_size;
  const float* x   = (const float*)d_in[0];
  const float* qst = (const float*)d_in[1];
  const float* g1w = (const float*)d_in[2];
  const float* g1b = (const float*)d_in[3];
  const float* g2w = (const float*)d_in[4];
  const float* g2b = (const float*)d_in[5];
  const float* g3w = (const float*)d_in[6];
  const float* g3b = (const float*)d_in[7];
  const float* g4w = (const float*)d_in[8];
  const float* g4b = (const float*)d_in[9];
  const float* f1w = (const float*)d_in[10];
  const float* f1b = (const float*)d_in[11];
  const float* f2w = (const float*)d_in[12];
  const float* f2b = (const float*)d_in[13];
  const float* f3w = (const float*)d_in[14];
  const float* f3b = (const float*)d_in[15];
  float* out = (float*)d_out;

  float*  A  = (float*)d_ws;
  float*  C  = A + 4096 * 256;
  bf16_t* Wt = (bf16_t*)(C + 4096 * 256);
  float*  xg = (float*)((char*)Wt + 3 * 65536 * sizeof(bf16_t));
  int*    cnt = (int*)(xg + 64 * 256);

  rn_prep_kernel<<<256 + 48 + 65, 256, 0, stream>>>(
      x, qst, g1w, g1b, g2w, g3w, g4w, A, C, Wt, xg, cnt);
  rn_main_kernel<<<2048, 256, 0, stream>>>(
      A, C, Wt, g2b, g3b, g4b, xg, cnt,
      f1w, f1b, f2w, f2b, f3w, f3b, out);
}